// Round 7
// baseline (173.776 us; speedup 1.0000x reference)
//
#include <hip/hip_runtime.h>
#include <hip/hip_bf16.h>
#include <math.h>

// SS2D (VMamba) forward, MI355X. Constants from the reference.
#define DM 96
#define DI 192
#define NS 16            // state dim N
#define KK 4             // directions
#define RR 6             // dt rank
#define HH 56
#define WW 56
#define LL (HH*WW)       // 3136
#define RN (RR + 2*NS)   // 38 rows of x_dbl
#define NCH 64           // scan chunks per sequence
#define CLL (LL/NCH)     // 49 steps per chunk

__device__ __forceinline__ float silu_f(float x) { return x / (1.f + __expf(-x)); }
__device__ __forceinline__ float softplus_f(float x) {
    return (x > 20.f) ? x : log1pf(__expf(x));
}

// K1: tiled GEMM xz[o][l]; 32l x 32o tiles, grid (98, 12).
// o<DI -> xc_t[o][l]; o>=DI -> silu -> z_nat[l][o-DI]
__global__ __launch_bounds__(256) void k_inproj(
        const float* __restrict__ x, const float* __restrict__ w,
        float* __restrict__ xc_t, float* __restrict__ z_nat) {
    __shared__ float xt[32 * 100];
    __shared__ float wt[32 * 100];
    const int l0 = blockIdx.x * 32;
    const int o0 = blockIdx.y * 32;
    const int tid = threadIdx.x;
    for (int i = tid; i < 32 * 24; i += 256) {          // float4 staging
        int r = i / 24, q = i % 24;
        *(float4*)&xt[r * 100 + 4 * q] = *(const float4*)&x[(size_t)(l0 + r) * DM + 4 * q];
        *(float4*)&wt[r * 100 + 4 * q] = *(const float4*)&w[(size_t)(o0 + r) * DM + 4 * q];
    }
    __syncthreads();
    const int tx = tid & 15, ty = tid >> 4;        // tx: o, ty: l
    float acc[2][2] = {};
    for (int c = 0; c < 96; c += 4) {
        float4 av[2], bv[2];
#pragma unroll
        for (int i = 0; i < 2; ++i) av[i] = *(const float4*)&xt[(ty + 16 * i) * 100 + c];
#pragma unroll
        for (int j = 0; j < 2; ++j) bv[j] = *(const float4*)&wt[(tx + 16 * j) * 100 + c];
#pragma unroll
        for (int i = 0; i < 2; ++i)
#pragma unroll
            for (int j = 0; j < 2; ++j) {
                acc[i][j] = fmaf(av[i].x, bv[j].x, acc[i][j]);
                acc[i][j] = fmaf(av[i].y, bv[j].y, acc[i][j]);
                acc[i][j] = fmaf(av[i].z, bv[j].z, acc[i][j]);
                acc[i][j] = fmaf(av[i].w, bv[j].w, acc[i][j]);
            }
    }
    __syncthreads();
    float* ot = xt;                                // reuse as [o][l] 32x65
#pragma unroll
    for (int j = 0; j < 2; ++j)
#pragma unroll
        for (int i = 0; i < 2; ++i)
            ot[(tx + 16 * j) * 65 + (ty + 16 * i)] = acc[i][j];
    __syncthreads();
    if (o0 < DI) {
        for (int i = tid; i < 32 * 32; i += 256) {
            int ol = i >> 5, ll = i & 31;
            xc_t[(size_t)(o0 + ol) * LL + l0 + ll] = ot[ol * 65 + ll];
        }
    } else {
        for (int i = tid; i < 32 * 32; i += 256) {
            int ll = i >> 5, ol = i & 31;
            z_nat[(size_t)(l0 + ll) * DI + (o0 - DI) + ol] = silu_f(ot[ol * 65 + ll]);
        }
    }
}

// K2: depthwise 3x3 conv SAME + bias + silu + spatial transpose, band-split.
__global__ __launch_bounds__(256) void k_convT(
        const float* __restrict__ xc_t, const float* __restrict__ cw,
        const float* __restrict__ cb, float* __restrict__ xconv, float* __restrict__ xs1) {
    __shared__ float in_s[16 * 56];
    __shared__ float out_s[14 * 57];
    const int d = blockIdx.x;
    const int h0 = blockIdx.y * 14;
    const int tid = threadIdx.x;
    const float* in = xc_t + (size_t)d * LL;
    for (int i = tid; i < 16 * 14; i += 256) {          // float4 staging
        int row = i / 14, q = i % 14;
        int r = row - 1 + h0;
        float4 v = make_float4(0.f, 0.f, 0.f, 0.f);
        if (r >= 0 && r < HH) v = *(const float4*)&in[r * WW + 4 * q];
        *(float4*)&in_s[row * 56 + 4 * q] = v;
    }
    __syncthreads();
    const float b0 = cb[d];
    float w9[9];
#pragma unroll
    for (int i = 0; i < 9; ++i) w9[i] = cw[d * 9 + i];
    for (int i = tid; i < 14 * 56; i += 256) {
        int hh = i / 56, w = i % 56;
        float acc = b0;
#pragma unroll
        for (int di = 0; di < 3; ++di)
#pragma unroll
            for (int dj = 0; dj < 3; ++dj) {
                int w2 = w + dj - 1;
                if (w2 < 0 || w2 >= WW) continue;
                acc = fmaf(in_s[(hh + di) * 56 + w2], w9[di * 3 + dj], acc);
            }
        acc = silu_f(acc);
        xconv[(size_t)d * LL + (h0 + hh) * WW + w] = acc;
        out_s[hh * 57 + w] = acc;
    }
    __syncthreads();
    for (int i = tid; i < 14 * 56; i += 256) {
        int w = i / 14, hh = i % 14;
        xs1[(size_t)d * LL + w * HH + h0 + hh] = out_s[hh * 57 + w];
    }
}

// K3: x_dbl + delta fused, l-tile 16. Both operands LDS-staged. Grid (196, 4).
// Bn/Cn written in SCAN-ORDER layout: [k][tl][chunk][n], pre-reversed for k>=2.
// delta stays in NATURAL layout (k_scan LDS-stages it coalesced).
__global__ __launch_bounds__(256) void k_xdblD(
        const float* __restrict__ xconv, const float* __restrict__ xs1,
        const float* __restrict__ pw, const float* __restrict__ dtw,
        const float* __restrict__ dtb,
        float* __restrict__ Bn, float* __restrict__ Cn, float* __restrict__ delta) {
    __shared__ float xt[DI * 16];                  // [d][sx], 12 KB
    __shared__ float wk_s[32 * DI];                // [col][d], 24.6 KB
    __shared__ float dtS[RR * 17];
    const int k = blockIdx.y;
    const int l0 = blockIdx.x * 16;
    const int tid = threadIdx.x;
    const float* in = (k & 1) ? xs1 : xconv;
    const float* wk = pw + (size_t)k * RN * DI;
    for (int i = tid; i < DI * 4; i += 256) {          // float4 staging
        int d = i >> 2, q = i & 3;
        *(float4*)&xt[(d << 4) + 4 * q] = *(const float4*)&in[(size_t)d * LL + l0 + 4 * q];
    }
    {
        const float4* src = (const float4*)(wk + RR * DI);
        float4* dst = (float4*)wk_s;
        for (int i = tid; i < (32 * DI) / 4; i += 256) dst[i] = src[i];
    }
    __syncthreads();
    if (tid < RR * 16) {
        int r = tid >> 4, lx = tid & 15;
        const float* wr = wk + r * DI;
        float acc = 0.f;
#pragma unroll 8
        for (int d = 0; d < DI; ++d) acc = fmaf(xt[(d << 4) + lx], wr[d], acc);
        dtS[r * 17 + lx] = acc;
    }
    {
        const int sx = tid & 15, cg = tid >> 4;    // cg in [0,16)
        float acc2[2] = {};
        for (int d = 0; d < DI; d += 4) {
            float x0 = xt[(d + 0) * 16 + sx];
            float x1 = xt[(d + 1) * 16 + sx];
            float x2 = xt[(d + 2) * 16 + sx];
            float x3 = xt[(d + 3) * 16 + sx];
#pragma unroll
            for (int j = 0; j < 2; ++j) {
                float4 wv = *(const float4*)&wk_s[(cg + 16 * j) * DI + d];
                acc2[j] = fmaf(x0, wv.x, acc2[j]);
                acc2[j] = fmaf(x1, wv.y, acc2[j]);
                acc2[j] = fmaf(x2, wv.z, acc2[j]);
                acc2[j] = fmaf(x3, wv.w, acc2[j]);
            }
        }
        int s = l0 + sx;
        int ss = (k < 2) ? s : (LL - 1 - s);       // scan-order index
        int cch = ss / CLL, ttl = ss - cch * CLL;
        size_t idx = ((size_t)k * LL + (size_t)ttl * NCH + cch) * NS + cg;
        Bn[idx] = acc2[0];                          // cols 0..15
        Cn[idx] = acc2[1];                          // cols 16..31
    }
    __syncthreads();
    for (int oi = tid; oi < DI * 16; oi += 256) {
        int d = oi >> 4, sl = oi & 15;
        int kd = k * DI + d;
        const float* wr = dtw + (size_t)kd * RR;
        float acc = dtb[kd];
#pragma unroll
        for (int r = 0; r < RR; ++r) acc = fmaf(dtS[r * 17 + sl], wr[r], acc);
        delta[(size_t)kd * LL + l0 + sl] = softplus_f(acc);
    }
}

// ---- templated scan body: 4 lanes per chunk, 4 contiguous states per lane.
// dl/u come from LDS (staged, broadcast); B/C from global in scan-order
// layout (step stride NCH*NS, coalesced 4KB/wave).
// LINEARITY SPLIT: phase 1 runs the local recurrence (h from 0) and emits
// yloc = C·hloc + D·u into yreg; phase 2 adds the carry correction
// y += (C ∘ exp2(An·cum))·h_in — NO serial recurrence, B read only once.
template<int STP, bool TRANS>
__device__ __forceinline__ void scan_dir(
        const float* sDel, const float* sU,        // LDS, pre-offset to im0
        const float* __restrict__ pB, const float* __restrict__ pC,
        float4 An, float Dv, int c, int n,
        float* __restrict__ sP, float* __restrict__ sH,
        float* __restrict__ yo0,   // !TRANS: direction-adjusted global base
        float* ysm,                // TRANS: LDS tile [HH][57] (aliases sDel buf)
        int im0) {
    // Phase 1: local scan (h=0 start) + local output dot
    float sd = 0.f;
    float4 h = make_float4(0.f, 0.f, 0.f, 0.f);
    float yreg[13];
#pragma unroll 7
    for (int tl = 0; tl < CLL; ++tl) {
        float dl = sDel[STP * tl];
        float u  = sU[STP * tl];
        float4 Bv = *(const float4*)&pB[(size_t)tl * (NCH * NS)];
        float4 Cv = *(const float4*)&pC[(size_t)tl * (NCH * NS)];
        float du = dl * u;
        h.x = fmaf(__builtin_amdgcn_exp2f(dl * An.x), h.x, du * Bv.x);
        h.y = fmaf(__builtin_amdgcn_exp2f(dl * An.y), h.y, du * Bv.y);
        h.z = fmaf(__builtin_amdgcn_exp2f(dl * An.z), h.z, du * Bv.z);
        h.w = fmaf(__builtin_amdgcn_exp2f(dl * An.w), h.w, du * Bv.w);
        float acc = h.x * Cv.x;
        acc = fmaf(h.y, Cv.y, acc);
        acc = fmaf(h.z, Cv.z, acc);
        acc = fmaf(h.w, Cv.w, acc);
        acc += __shfl_xor(acc, 2, 64);
        acc += __shfl_xor(acc, 1, 64);
        acc = fmaf(Dv, u, acc);
        sd += dl;
        if ((tl & 3) == n) yreg[tl >> 2] = acc;
    }
    *(float4*)&sP[c * NS + 4 * n] = make_float4(
        __builtin_amdgcn_exp2f(sd * An.x), __builtin_amdgcn_exp2f(sd * An.y),
        __builtin_amdgcn_exp2f(sd * An.z), __builtin_amdgcn_exp2f(sd * An.w));
    *(float4*)&sH[c * NS + 4 * n] = h;
    __syncthreads();
    float4 hin = make_float4(0.f, 0.f, 0.f, 0.f);
    for (int cc = 0; cc < c; ++cc) {
        float4 P  = *(const float4*)&sP[cc * NS + 4 * n];
        float4 Hh = *(const float4*)&sH[cc * NS + 4 * n];
        hin.x = fmaf(P.x, hin.x, Hh.x);
        hin.y = fmaf(P.y, hin.y, Hh.y);
        hin.z = fmaf(P.z, hin.z, Hh.z);
        hin.w = fmaf(P.w, hin.w, Hh.w);
    }

    // Phase 2: parallel carry correction (no recurrence; C re-read only)
    float cum = 0.f;
#pragma unroll 7
    for (int tl = 0; tl < CLL; ++tl) {
        float dl = sDel[STP * tl];
        cum += dl;
        float4 Cv = *(const float4*)&pC[(size_t)tl * (NCH * NS)];
        float corr = (hin.x * __builtin_amdgcn_exp2f(cum * An.x)) * Cv.x;
        corr = fmaf(hin.y * __builtin_amdgcn_exp2f(cum * An.y), Cv.y, corr);
        corr = fmaf(hin.z * __builtin_amdgcn_exp2f(cum * An.z), Cv.z, corr);
        corr = fmaf(hin.w * __builtin_amdgcn_exp2f(cum * An.w), Cv.w, corr);
        corr += __shfl_xor(corr, 2, 64);
        corr += __shfl_xor(corr, 1, 64);
        if ((tl & 3) == n) yreg[tl >> 2] += corr;
    }
    if (!TRANS) {
#pragma unroll
        for (int j = 0; j < 12; ++j)
            yo0[STP * (j * 4 + n)] = yreg[j];
        if (n == 0)
            yo0[STP * 48] = yreg[12];
    } else {
        __syncthreads();   // all waves done reading sDel/sU before ysm reuse
#pragma unroll
        for (int j = 0; j < 12; ++j) {
            int im = im0 + STP * (j * 4 + n);
            int w = im / HH, hh = im - w * HH;
            ysm[hh * 57 + w] = yreg[j];
        }
        if (n == 0) {
            int im = im0 + STP * 48;
            int w = im / HH, hh = im - w * HH;
            ysm[hh * 57 + w] = yreg[12];
        }
    }
}

// K4: chunked selective scan; 256 threads (4 waves), 64 chunks x 4 lanes.
// delta/u rows fully LDS-staged (coalesced); B/C read in scan-order layout.
// One (k,d) per block -> grid KK*DI = 768 (3 blocks/CU, 12 waves/CU).
__global__ __launch_bounds__(256) void k_scan(
        const float* __restrict__ delta, const float* __restrict__ Bn,
        const float* __restrict__ Cn,
        const float* __restrict__ xconv, const float* __restrict__ xs1,
        const float* __restrict__ A_logs, const float* __restrict__ Ds,
        float* __restrict__ y4) {
    __shared__ float sbuf[2 * LL];                 // del row | u row; reused as ys
    __shared__ float sP[NCH * NS];
    __shared__ float sH[NCH * NS];
    int b = blockIdx.x;
    int k = b / DI, d = b % DI;
    int tid = threadIdx.x;
    int c = tid >> 2, n = tid & 3;
    int kd = k * DI + d;
    const float LOG2E = 1.4426950408889634f;
    float4 Alg = *(const float4*)&A_logs[kd * NS + 4 * n];
    float4 An = make_float4(-__expf(Alg.x) * LOG2E, -__expf(Alg.y) * LOG2E,
                            -__expf(Alg.z) * LOG2E, -__expf(Alg.w) * LOG2E);
    float Dv = Ds[kd];
    const float* del = delta + (size_t)kd * LL;
    const float* uP  = ((k & 1) ? xs1 : xconv) + (size_t)d * LL;
    // coalesced staging of delta row and u row
    {
        const float4* s1 = (const float4*)del;
        const float4* s2 = (const float4*)uP;
        float4* d1 = (float4*)sbuf;
        float4* d2 = (float4*)(sbuf + LL);
        for (int i = tid; i < LL / 4; i += 256) {
            d1[i] = s1[i];
            d2[i] = s2[i];
        }
    }
    __syncthreads();
    const float* Bb = Bn + (size_t)k * LL * NS + c * NS + 4 * n;
    const float* Cb = Cn + (size_t)k * LL * NS + c * NS + 4 * n;
    float* yo = y4 + (size_t)kd * LL;
    const int t0 = c * CLL;
    const int imF = t0;                  // forward base
    const int imR = LL - 1 - t0;         // reverse base
    if (k == 0) {
        scan_dir<1, false>(sbuf + imF, sbuf + LL + imF, Bb, Cb,
                           An, Dv, c, n, sP, sH, yo + imF, nullptr, 0);
    } else if (k == 1) {
        scan_dir<1, true>(sbuf + imF, sbuf + LL + imF, Bb, Cb,
                          An, Dv, c, n, sP, sH, nullptr, sbuf, imF);
    } else if (k == 2) {
        scan_dir<-1, false>(sbuf + imR, sbuf + LL + imR, Bb, Cb,
                            An, Dv, c, n, sP, sH, yo + imR, nullptr, 0);
    } else {
        scan_dir<-1, true>(sbuf + imR, sbuf + LL + imR, Bb, Cb,
                           An, Dv, c, n, sP, sH, nullptr, sbuf, imR);
    }
    if (k & 1) {                         // block-uniform branch
        __syncthreads();
        for (int p = tid; p < LL; p += 256)
            yo[p] = sbuf[p + p / WW];    // [h][w] tile, stride 57
    }
}

// K5: merge 4 natural rows + LayerNorm + gate(z), then ONE 48-o out-proj pass
// per block (pass = blockIdx.y). Grid (196, 2). ow_s staged concurrently with
// the merge (independent phases share the first barrier).
__global__ __launch_bounds__(256) void k_lnout(
        const float* __restrict__ y4, const float* __restrict__ z_nat,
        const float* __restrict__ lnw, const float* __restrict__ lnb,
        const float* __restrict__ ow, float* __restrict__ out) {
    __shared__ float yv[16 * 196];                 // 12.5 KB
    __shared__ float ow_s[48 * 196];               // 37.6 KB
    __shared__ float mean_s[16], inv_s[16];
    const int l0 = blockIdx.x * 16;
    const int pass = blockIdx.y;
    const int tid = threadIdx.x;
    // stage this pass's out-proj weights (independent of merge)
    for (int i = tid; i < 48 * 48; i += 256) {
        int o = i / 48, q = i % 48;
        *(float4*)&ow_s[o * 196 + 4 * q] =
            *(const float4*)&ow[(size_t)(pass * 48 + o) * DI + 4 * q];
    }
    // merge 4 directions: float4 over p for each d
    for (int i = tid; i < DI * 4; i += 256) {
        int d = i >> 2, q = i & 3;
        size_t off = (size_t)d * LL + l0 + 4 * q;
        float4 a = *(const float4*)&y4[off];
        float4 b = *(const float4*)&y4[(size_t)DI * LL + off];
        float4 c2 = *(const float4*)&y4[(size_t)(2 * DI) * LL + off];
        float4 e = *(const float4*)&y4[(size_t)(3 * DI) * LL + off];
        int p = 4 * q;
        yv[(p + 0) * 196 + d] = a.x + b.x + c2.x + e.x;
        yv[(p + 1) * 196 + d] = a.y + b.y + c2.y + e.y;
        yv[(p + 2) * 196 + d] = a.z + b.z + c2.z + e.z;
        yv[(p + 3) * 196 + d] = a.w + b.w + c2.w + e.w;
    }
    __syncthreads();
    // LN stats: 16 lanes per p
    {
        int p = tid >> 4, e = tid & 15;
        float s1 = 0.f;
#pragma unroll
        for (int m = 0; m < 12; ++m) s1 += yv[p * 196 + e + 16 * m];
        s1 += __shfl_xor(s1, 8, 64);
        s1 += __shfl_xor(s1, 4, 64);
        s1 += __shfl_xor(s1, 2, 64);
        s1 += __shfl_xor(s1, 1, 64);
        float mean = s1 * (1.f / DI);
        float s2 = 0.f;
#pragma unroll
        for (int m = 0; m < 12; ++m) {
            float dv = yv[p * 196 + e + 16 * m] - mean;
            s2 = fmaf(dv, dv, s2);
        }
        s2 += __shfl_xor(s2, 8, 64);
        s2 += __shfl_xor(s2, 4, 64);
        s2 += __shfl_xor(s2, 2, 64);
        s2 += __shfl_xor(s2, 1, 64);
        if (e == 0) {
            mean_s[p] = mean;
            inv_s[p] = rsqrtf(s2 * (1.f / DI) + 1e-5f);
        }
    }
    __syncthreads();
    // normalize + gate (float4 over d)
    for (int i = tid; i < 16 * 48; i += 256) {
        int p = i / 48, q = i % 48;
        float4 z4 = *(const float4*)&z_nat[(size_t)(l0 + p) * DI + 4 * q];
        float4 w4 = *(const float4*)&lnw[4 * q];
        float4 b4 = *(const float4*)&lnb[4 * q];
        float4 yy = *(const float4*)&yv[p * 196 + 4 * q];
        float m = mean_s[p], iv = inv_s[p];
        yy.x = ((yy.x - m) * iv * w4.x + b4.x) * z4.x;
        yy.y = ((yy.y - m) * iv * w4.y + b4.y) * z4.y;
        yy.z = ((yy.z - m) * iv * w4.z + b4.z) * z4.z;
        yy.w = ((yy.w - m) * iv * w4.w + b4.w) * z4.w;
        *(float4*)&yv[p * 196 + 4 * q] = yy;
    }
    __syncthreads();
    // out-proj: single 48-o pass
    const int ty = tid >> 4, tx = tid & 15;        // ty: l, tx: o
    float acc[3] = {};
    for (int dd = 0; dd < DI; dd += 4) {
        float4 a0 = *(const float4*)&yv[ty * 196 + dd];
#pragma unroll
        for (int j = 0; j < 3; ++j) {
            float4 bv = *(const float4*)&ow_s[(tx + 16 * j) * 196 + dd];
            acc[j] += a0.x * bv.x + a0.y * bv.y + a0.z * bv.z + a0.w * bv.w;
        }
    }
#pragma unroll
    for (int j = 0; j < 3; ++j)
        out[(size_t)(l0 + ty) * DM + pass * 48 + tx + 16 * j] = acc[j];
}

extern "C" void kernel_launch(void* const* d_in, const int* in_sizes, int n_in,
                              void* d_out, int out_size, void* d_ws, size_t ws_size,
                              hipStream_t stream) {
    const float* x    = (const float*)d_in[0];
    const float* ipw  = (const float*)d_in[1];
    const float* cw   = (const float*)d_in[2];
    const float* cb   = (const float*)d_in[3];
    const float* xpw  = (const float*)d_in[4];
    const float* dtw  = (const float*)d_in[5];
    const float* dtb  = (const float*)d_in[6];
    const float* alog = (const float*)d_in[7];
    const float* Dsp  = (const float*)d_in[8];
    const float* lnw  = (const float*)d_in[9];
    const float* lnb  = (const float*)d_in[10];
    const float* ow   = (const float*)d_in[11];
    float* out = (float*)d_out;

    float* ws     = (float*)d_ws;
    float* xc_t   = ws;                             // DI*LL (dead after convT)
    float* z_nat  = xc_t + DI * LL;                 // LL*DI
    float* xconv  = z_nat + DI * LL;                // DI*LL
    float* xs1    = xconv + DI * LL;                // DI*LL
    float* Bn     = xs1 + DI * LL;                  // KK*LL*NS (scan-order layout)
    float* Cn     = Bn + (size_t)KK * LL * NS;      // KK*LL*NS (scan-order layout)
    float* delta  = Cn + (size_t)KK * LL * NS;      // KK*DI*LL (natural layout)
    float* y4     = delta + (size_t)KK * DI * LL;   // KK*DI*LL (natural p)

    k_inproj <<<dim3(LL / 32, 12), 256, 0, stream>>>(x, ipw, xc_t, z_nat);
    k_convT  <<<dim3(DI, 4), 256, 0, stream>>>(xc_t, cw, cb, xconv, xs1);
    k_xdblD  <<<dim3(LL / 16, KK), 256, 0, stream>>>(xconv, xs1, xpw, dtw, dtb, Bn, Cn, delta);
    k_scan   <<<KK * DI, 256, 0, stream>>>(delta, Bn, Cn, xconv, xs1, alog, Dsp, y4);
    k_lnout  <<<dim3(LL / 16, 2), 256, 0, stream>>>(y4, z_nat, lnw, lnb, ow, out);
}

// Round 9
// 171.007 us; speedup vs baseline: 1.0162x; 1.0162x over previous
//
#include <hip/hip_runtime.h>
#include <hip/hip_bf16.h>
#include <math.h>

// SS2D (VMamba) forward, MI355X. Constants from the reference.
#define DM 96
#define DI 192
#define NS 16            // state dim N
#define KK 4             // directions
#define RR 6             // dt rank
#define HH 56
#define WW 56
#define LL (HH*WW)       // 3136
#define RN (RR + 2*NS)   // 38 rows of x_dbl
#define NCH 64           // scan chunks per sequence
#define CLL (LL/NCH)     // 49 steps per chunk

__device__ __forceinline__ float silu_f(float x) { return x / (1.f + __expf(-x)); }
__device__ __forceinline__ float softplus_f(float x) {
    return (x > 20.f) ? x : log1pf(__expf(x));
}

// K1: tiled GEMM xz[o][l]; 32l x 32o tiles, grid (98, 12).
// o<DI -> xc_t[o][l]; o>=DI -> silu -> z_nat[l][o-DI]
__global__ __launch_bounds__(256) void k_inproj(
        const float* __restrict__ x, const float* __restrict__ w,
        float* __restrict__ xc_t, float* __restrict__ z_nat) {
    __shared__ float xt[32 * 100];
    __shared__ float wt[32 * 100];
    const int l0 = blockIdx.x * 32;
    const int o0 = blockIdx.y * 32;
    const int tid = threadIdx.x;
    for (int i = tid; i < 32 * 24; i += 256) {          // float4 staging
        int r = i / 24, q = i % 24;
        *(float4*)&xt[r * 100 + 4 * q] = *(const float4*)&x[(size_t)(l0 + r) * DM + 4 * q];
        *(float4*)&wt[r * 100 + 4 * q] = *(const float4*)&w[(size_t)(o0 + r) * DM + 4 * q];
    }
    __syncthreads();
    const int tx = tid & 15, ty = tid >> 4;        // tx: o, ty: l
    float acc[2][2] = {};
    for (int c = 0; c < 96; c += 4) {
        float4 av[2], bv[2];
#pragma unroll
        for (int i = 0; i < 2; ++i) av[i] = *(const float4*)&xt[(ty + 16 * i) * 100 + c];
#pragma unroll
        for (int j = 0; j < 2; ++j) bv[j] = *(const float4*)&wt[(tx + 16 * j) * 100 + c];
#pragma unroll
        for (int i = 0; i < 2; ++i)
#pragma unroll
            for (int j = 0; j < 2; ++j) {
                acc[i][j] = fmaf(av[i].x, bv[j].x, acc[i][j]);
                acc[i][j] = fmaf(av[i].y, bv[j].y, acc[i][j]);
                acc[i][j] = fmaf(av[i].z, bv[j].z, acc[i][j]);
                acc[i][j] = fmaf(av[i].w, bv[j].w, acc[i][j]);
            }
    }
    __syncthreads();
    float* ot = xt;                                // reuse as [o][l] 32x65
#pragma unroll
    for (int j = 0; j < 2; ++j)
#pragma unroll
        for (int i = 0; i < 2; ++i)
            ot[(tx + 16 * j) * 65 + (ty + 16 * i)] = acc[i][j];
    __syncthreads();
    if (o0 < DI) {
        for (int i = tid; i < 32 * 32; i += 256) {
            int ol = i >> 5, ll = i & 31;
            xc_t[(size_t)(o0 + ol) * LL + l0 + ll] = ot[ol * 65 + ll];
        }
    } else {
        for (int i = tid; i < 32 * 32; i += 256) {
            int ll = i >> 5, ol = i & 31;
            z_nat[(size_t)(l0 + ll) * DI + (o0 - DI) + ol] = silu_f(ot[ol * 65 + ll]);
        }
    }
}

// K2: depthwise 3x3 conv SAME + bias + silu + spatial transpose, band-split.
__global__ __launch_bounds__(256) void k_convT(
        const float* __restrict__ xc_t, const float* __restrict__ cw,
        const float* __restrict__ cb, float* __restrict__ xconv, float* __restrict__ xs1) {
    __shared__ float in_s[16 * 56];
    __shared__ float out_s[14 * 57];
    const int d = blockIdx.x;
    const int h0 = blockIdx.y * 14;
    const int tid = threadIdx.x;
    const float* in = xc_t + (size_t)d * LL;
    for (int i = tid; i < 16 * 14; i += 256) {          // float4 staging
        int row = i / 14, q = i % 14;
        int r = row - 1 + h0;
        float4 v = make_float4(0.f, 0.f, 0.f, 0.f);
        if (r >= 0 && r < HH) v = *(const float4*)&in[r * WW + 4 * q];
        *(float4*)&in_s[row * 56 + 4 * q] = v;
    }
    __syncthreads();
    const float b0 = cb[d];
    float w9[9];
#pragma unroll
    for (int i = 0; i < 9; ++i) w9[i] = cw[d * 9 + i];
    for (int i = tid; i < 14 * 56; i += 256) {
        int hh = i / 56, w = i % 56;
        float acc = b0;
#pragma unroll
        for (int di = 0; di < 3; ++di)
#pragma unroll
            for (int dj = 0; dj < 3; ++dj) {
                int w2 = w + dj - 1;
                if (w2 < 0 || w2 >= WW) continue;
                acc = fmaf(in_s[(hh + di) * 56 + w2], w9[di * 3 + dj], acc);
            }
        acc = silu_f(acc);
        xconv[(size_t)d * LL + (h0 + hh) * WW + w] = acc;
        out_s[hh * 57 + w] = acc;
    }
    __syncthreads();
    for (int i = tid; i < 14 * 56; i += 256) {
        int w = i / 14, hh = i % 14;
        xs1[(size_t)d * LL + w * HH + h0 + hh] = out_s[hh * 57 + w];
    }
}

// K3: x_dbl + delta fused, l-tile 16. Both operands LDS-staged. Grid (196, 4).
// Bn/Cn written in SCAN-ORDER layout: [k][tl][chunk][n], pre-reversed for k>=2.
// delta stays in NATURAL layout (k_scan LDS-stages it coalesced).
__global__ __launch_bounds__(256) void k_xdblD(
        const float* __restrict__ xconv, const float* __restrict__ xs1,
        const float* __restrict__ pw, const float* __restrict__ dtw,
        const float* __restrict__ dtb,
        float* __restrict__ Bn, float* __restrict__ Cn, float* __restrict__ delta) {
    __shared__ float xt[DI * 16];                  // [d][sx], 12 KB
    __shared__ float wk_s[32 * DI];                // [col][d], 24.6 KB
    __shared__ float dtS[RR * 17];
    const int k = blockIdx.y;
    const int l0 = blockIdx.x * 16;
    const int tid = threadIdx.x;
    const float* in = (k & 1) ? xs1 : xconv;
    const float* wk = pw + (size_t)k * RN * DI;
    for (int i = tid; i < DI * 4; i += 256) {          // float4 staging
        int d = i >> 2, q = i & 3;
        *(float4*)&xt[(d << 4) + 4 * q] = *(const float4*)&in[(size_t)d * LL + l0 + 4 * q];
    }
    {
        const float4* src = (const float4*)(wk + RR * DI);
        float4* dst = (float4*)wk_s;
        for (int i = tid; i < (32 * DI) / 4; i += 256) dst[i] = src[i];
    }
    __syncthreads();
    if (tid < RR * 16) {
        int r = tid >> 4, lx = tid & 15;
        const float* wr = wk + r * DI;
        float acc = 0.f;
#pragma unroll 8
        for (int d = 0; d < DI; ++d) acc = fmaf(xt[(d << 4) + lx], wr[d], acc);
        dtS[r * 17 + lx] = acc;
    }
    {
        const int sx = tid & 15, cg = tid >> 4;    // cg in [0,16)
        float acc2[2] = {};
        for (int d = 0; d < DI; d += 4) {
            float x0 = xt[(d + 0) * 16 + sx];
            float x1 = xt[(d + 1) * 16 + sx];
            float x2 = xt[(d + 2) * 16 + sx];
            float x3 = xt[(d + 3) * 16 + sx];
#pragma unroll
            for (int j = 0; j < 2; ++j) {
                float4 wv = *(const float4*)&wk_s[(cg + 16 * j) * DI + d];
                acc2[j] = fmaf(x0, wv.x, acc2[j]);
                acc2[j] = fmaf(x1, wv.y, acc2[j]);
                acc2[j] = fmaf(x2, wv.z, acc2[j]);
                acc2[j] = fmaf(x3, wv.w, acc2[j]);
            }
        }
        int s = l0 + sx;
        int ss = (k < 2) ? s : (LL - 1 - s);       // scan-order index
        int cch = ss / CLL, ttl = ss - cch * CLL;
        size_t idx = ((size_t)k * LL + (size_t)ttl * NCH + cch) * NS + cg;
        Bn[idx] = acc2[0];                          // cols 0..15
        Cn[idx] = acc2[1];                          // cols 16..31
    }
    __syncthreads();
    for (int oi = tid; oi < DI * 16; oi += 256) {
        int d = oi >> 4, sl = oi & 15;
        int kd = k * DI + d;
        const float* wr = dtw + (size_t)kd * RR;
        float acc = dtb[kd];
#pragma unroll
        for (int r = 0; r < RR; ++r) acc = fmaf(dtS[r * 17 + sl], wr[r], acc);
        delta[(size_t)kd * LL + l0 + sl] = softplus_f(acc);
    }
}

// ---- templated scan body: 8 lanes per chunk, 2 contiguous states per lane.
// dl/u from LDS (staged, broadcast across the 8 lanes of a chunk);
// B/C from global in scan-order layout (step stride NCH*NS, coalesced
// 512B/wave/step in float2 granules).
// STP = +/-1 applies only to the LDS position indexing and y emission.
template<int STP, bool TRANS>
__device__ __forceinline__ void scan_dir(
        const float* sDel, const float* sU,        // LDS, pre-offset to im0
        const float* __restrict__ pB, const float* __restrict__ pC, // at +2n
        float2 An, float Dv, int c, int n,
        float* __restrict__ sP, float* __restrict__ sH,
        float* __restrict__ yo0,   // !TRANS: direction-adjusted global base
        float* ysm,                // TRANS: LDS tile [HH][57] (aliases sDel buf)
        int im0) {
    // Phase 1: chunk-local scan (h=0 start); P = exp2(An * sum(dl))
    float sd = 0.f;
    float2 h = make_float2(0.f, 0.f);
#pragma unroll 7
    for (int tl = 0; tl < CLL; ++tl) {
        float dl = sDel[STP * tl];
        float u  = sU[STP * tl];
        float2 Bv = *(const float2*)&pB[(size_t)tl * (NCH * NS)];
        float du = dl * u;
        h.x = fmaf(__builtin_amdgcn_exp2f(dl * An.x), h.x, du * Bv.x);
        h.y = fmaf(__builtin_amdgcn_exp2f(dl * An.y), h.y, du * Bv.y);
        sd += dl;
    }
    *(float2*)&sP[c * NS + 2 * n] = make_float2(
        __builtin_amdgcn_exp2f(sd * An.x), __builtin_amdgcn_exp2f(sd * An.y));
    *(float2*)&sH[c * NS + 2 * n] = h;
    __syncthreads();
    float2 hin = make_float2(0.f, 0.f);
    for (int cc = 0; cc < c; ++cc) {
        float2 P  = *(const float2*)&sP[cc * NS + 2 * n];
        float2 Hh = *(const float2*)&sH[cc * NS + 2 * n];
        hin.x = fmaf(P.x, hin.x, Hh.x);
        hin.y = fmaf(P.y, hin.y, Hh.y);
    }

    // Phase 2: rescan with carry, emit y
    float2 h2 = hin;
    float yreg[7];
#pragma unroll 7
    for (int tl = 0; tl < CLL; ++tl) {
        float dl = sDel[STP * tl];
        float u  = sU[STP * tl];
        float2 Bv = *(const float2*)&pB[(size_t)tl * (NCH * NS)];
        float2 Cv = *(const float2*)&pC[(size_t)tl * (NCH * NS)];
        float du = dl * u;
        h2.x = fmaf(__builtin_amdgcn_exp2f(dl * An.x), h2.x, du * Bv.x);
        h2.y = fmaf(__builtin_amdgcn_exp2f(dl * An.y), h2.y, du * Bv.y);
        float acc = h2.x * Cv.x;
        acc = fmaf(h2.y, Cv.y, acc);
        acc += __shfl_xor(acc, 4, 64);
        acc += __shfl_xor(acc, 2, 64);
        acc += __shfl_xor(acc, 1, 64);
        acc = fmaf(Dv, u, acc);
        if ((tl & 7) == n) yreg[tl >> 3] = acc;
    }
    if (!TRANS) {
#pragma unroll
        for (int j = 0; j < 6; ++j)
            yo0[STP * (j * 8 + n)] = yreg[j];
        if (n == 0)
            yo0[STP * 48] = yreg[6];
    } else {
        __syncthreads();   // all waves done reading sDel/sU before ysm reuse
#pragma unroll
        for (int j = 0; j < 6; ++j) {
            int im = im0 + STP * (j * 8 + n);
            int w = im / HH, hh = im - w * HH;
            ysm[hh * 57 + w] = yreg[j];
        }
        if (n == 0) {
            int im = im0 + STP * 48;
            int w = im / HH, hh = im - w * HH;
            ysm[hh * 57 + w] = yreg[6];
        }
    }
}

// K4: chunked selective scan; 512 threads (8 waves), 64 chunks x 8 lanes.
// delta/u rows fully LDS-staged (coalesced); B/C read in scan-order layout.
// One (k,d) per block -> grid KK*DI = 768 (3 blocks/CU, 24 waves/CU).
__global__ __launch_bounds__(512) void k_scan(
        const float* __restrict__ delta, const float* __restrict__ Bn,
        const float* __restrict__ Cn,
        const float* __restrict__ xconv, const float* __restrict__ xs1,
        const float* __restrict__ A_logs, const float* __restrict__ Ds,
        float* __restrict__ y4) {
    __shared__ float sbuf[2 * LL];                 // del row | u row; reused as ys
    __shared__ float sP[NCH * NS];
    __shared__ float sH[NCH * NS];
    int b = blockIdx.x;
    int k = b / DI, d = b % DI;
    int tid = threadIdx.x;
    int c = tid >> 3, n = tid & 7;
    int kd = k * DI + d;
    const float LOG2E = 1.4426950408889634f;
    float2 Alg = *(const float2*)&A_logs[kd * NS + 2 * n];
    float2 An = make_float2(-__expf(Alg.x) * LOG2E, -__expf(Alg.y) * LOG2E);
    float Dv = Ds[kd];
    const float* del = delta + (size_t)kd * LL;
    const float* uP  = ((k & 1) ? xs1 : xconv) + (size_t)d * LL;
    // coalesced staging of delta row and u row
    {
        const float4* s1 = (const float4*)del;
        const float4* s2 = (const float4*)uP;
        float4* d1 = (float4*)sbuf;
        float4* d2 = (float4*)(sbuf + LL);
        for (int i = tid; i < LL / 4; i += 512) {
            d1[i] = s1[i];
            d2[i] = s2[i];
        }
    }
    __syncthreads();
    const float* Bb = Bn + (size_t)k * LL * NS + c * NS + 2 * n;
    const float* Cb = Cn + (size_t)k * LL * NS + c * NS + 2 * n;
    float* yo = y4 + (size_t)kd * LL;
    const int t0 = c * CLL;
    const int imF = t0;                  // forward base
    const int imR = LL - 1 - t0;         // reverse base
    if (k == 0) {
        scan_dir<1, false>(sbuf + imF, sbuf + LL + imF, Bb, Cb,
                           An, Dv, c, n, sP, sH, yo + imF, nullptr, 0);
    } else if (k == 1) {
        scan_dir<1, true>(sbuf + imF, sbuf + LL + imF, Bb, Cb,
                          An, Dv, c, n, sP, sH, nullptr, sbuf, imF);
    } else if (k == 2) {
        scan_dir<-1, false>(sbuf + imR, sbuf + LL + imR, Bb, Cb,
                            An, Dv, c, n, sP, sH, yo + imR, nullptr, 0);
    } else {
        scan_dir<-1, true>(sbuf + imR, sbuf + LL + imR, Bb, Cb,
                           An, Dv, c, n, sP, sH, nullptr, sbuf, imR);
    }
    if (k & 1) {                         // block-uniform branch
        __syncthreads();
        for (int p = tid; p < LL; p += 512)
            yo[p] = sbuf[p + p / WW];    // [h][w] tile, stride 57
    }
}

// K5: merge 4 natural rows + LayerNorm + gate(z), then ONE 48-o out-proj pass
// per block (pass = blockIdx.y). Grid (196, 2). ow_s staged concurrently with
// the merge (independent phases share the first barrier).
__global__ __launch_bounds__(256) void k_lnout(
        const float* __restrict__ y4, const float* __restrict__ z_nat,
        const float* __restrict__ lnw, const float* __restrict__ lnb,
        const float* __restrict__ ow, float* __restrict__ out) {
    __shared__ float yv[16 * 196];                 // 12.5 KB
    __shared__ float ow_s[48 * 196];               // 37.6 KB
    __shared__ float mean_s[16], inv_s[16];
    const int l0 = blockIdx.x * 16;
    const int pass = blockIdx.y;
    const int tid = threadIdx.x;
    // stage this pass's out-proj weights (independent of merge)
    for (int i = tid; i < 48 * 48; i += 256) {
        int o = i / 48, q = i % 48;
        *(float4*)&ow_s[o * 196 + 4 * q] =
            *(const float4*)&ow[(size_t)(pass * 48 + o) * DI + 4 * q];
    }
    // merge 4 directions: float4 over p for each d
    for (int i = tid; i < DI * 4; i += 256) {
        int d = i >> 2, q = i & 3;
        size_t off = (size_t)d * LL + l0 + 4 * q;
        float4 a = *(const float4*)&y4[off];
        float4 b = *(const float4*)&y4[(size_t)DI * LL + off];
        float4 c2 = *(const float4*)&y4[(size_t)(2 * DI) * LL + off];
        float4 e = *(const float4*)&y4[(size_t)(3 * DI) * LL + off];
        int p = 4 * q;
        yv[(p + 0) * 196 + d] = a.x + b.x + c2.x + e.x;
        yv[(p + 1) * 196 + d] = a.y + b.y + c2.y + e.y;
        yv[(p + 2) * 196 + d] = a.z + b.z + c2.z + e.z;
        yv[(p + 3) * 196 + d] = a.w + b.w + c2.w + e.w;
    }
    __syncthreads();
    // LN stats: 16 lanes per p
    {
        int p = tid >> 4, e = tid & 15;
        float s1 = 0.f;
#pragma unroll
        for (int m = 0; m < 12; ++m) s1 += yv[p * 196 + e + 16 * m];
        s1 += __shfl_xor(s1, 8, 64);
        s1 += __shfl_xor(s1, 4, 64);
        s1 += __shfl_xor(s1, 2, 64);
        s1 += __shfl_xor(s1, 1, 64);
        float mean = s1 * (1.f / DI);
        float s2 = 0.f;
#pragma unroll
        for (int m = 0; m < 12; ++m) {
            float dv = yv[p * 196 + e + 16 * m] - mean;
            s2 = fmaf(dv, dv, s2);
        }
        s2 += __shfl_xor(s2, 8, 64);
        s2 += __shfl_xor(s2, 4, 64);
        s2 += __shfl_xor(s2, 2, 64);
        s2 += __shfl_xor(s2, 1, 64);
        if (e == 0) {
            mean_s[p] = mean;
            inv_s[p] = rsqrtf(s2 * (1.f / DI) + 1e-5f);
        }
    }
    __syncthreads();
    // normalize + gate (float4 over d)
    for (int i = tid; i < 16 * 48; i += 256) {
        int p = i / 48, q = i % 48;
        float4 z4 = *(const float4*)&z_nat[(size_t)(l0 + p) * DI + 4 * q];
        float4 w4 = *(const float4*)&lnw[4 * q];
        float4 b4 = *(const float4*)&lnb[4 * q];
        float4 yy = *(const float4*)&yv[p * 196 + 4 * q];
        float m = mean_s[p], iv = inv_s[p];
        yy.x = ((yy.x - m) * iv * w4.x + b4.x) * z4.x;
        yy.y = ((yy.y - m) * iv * w4.y + b4.y) * z4.y;
        yy.z = ((yy.z - m) * iv * w4.z + b4.z) * z4.z;
        yy.w = ((yy.w - m) * iv * w4.w + b4.w) * z4.w;
        *(float4*)&yv[p * 196 + 4 * q] = yy;
    }
    __syncthreads();
    // out-proj: single 48-o pass
    const int ty = tid >> 4, tx = tid & 15;        // ty: l, tx: o
    float acc[3] = {};
    for (int dd = 0; dd < DI; dd += 4) {
        float4 a0 = *(const float4*)&yv[ty * 196 + dd];
#pragma unroll
        for (int j = 0; j < 3; ++j) {
            float4 bv = *(const float4*)&ow_s[(tx + 16 * j) * 196 + dd];
            acc[j] += a0.x * bv.x + a0.y * bv.y + a0.z * bv.z + a0.w * bv.w;
        }
    }
#pragma unroll
    for (int j = 0; j < 3; ++j)
        out[(size_t)(l0 + ty) * DM + pass * 48 + tx + 16 * j] = acc[j];
}

extern "C" void kernel_launch(void* const* d_in, const int* in_sizes, int n_in,
                              void* d_out, int out_size, void* d_ws, size_t ws_size,
                              hipStream_t stream) {
    const float* x    = (const float*)d_in[0];
    const float* ipw  = (const float*)d_in[1];
    const float* cw   = (const float*)d_in[2];
    const float* cb   = (const float*)d_in[3];
    const float* xpw  = (const float*)d_in[4];
    const float* dtw  = (const float*)d_in[5];
    const float* dtb  = (const float*)d_in[6];
    const float* alog = (const float*)d_in[7];
    const float* Dsp  = (const float*)d_in[8];
    const float* lnw  = (const float*)d_in[9];
    const float* lnb  = (const float*)d_in[10];
    const float* ow   = (const float*)d_in[11];
    float* out = (float*)d_out;

    float* ws     = (float*)d_ws;
    float* xc_t   = ws;                             // DI*LL (dead after convT)
    float* z_nat  = xc_t + DI * LL;                 // LL*DI
    float* xconv  = z_nat + DI * LL;                // DI*LL
    float* xs1    = xconv + DI * LL;                // DI*LL
    float* Bn     = xs1 + DI * LL;                  // KK*LL*NS (scan-order layout)
    float* Cn     = Bn + (size_t)KK * LL * NS;      // KK*LL*NS (scan-order layout)
    float* delta  = Cn + (size_t)KK * LL * NS;      // KK*DI*LL (natural layout)
    float* y4     = delta + (size_t)KK * DI * LL;   // KK*DI*LL (natural p)

    k_inproj <<<dim3(LL / 32, 12), 256, 0, stream>>>(x, ipw, xc_t, z_nat);
    k_convT  <<<dim3(DI, 4), 256, 0, stream>>>(xc_t, cw, cb, xconv, xs1);
    k_xdblD  <<<dim3(LL / 16, KK), 256, 0, stream>>>(xconv, xs1, xpw, dtw, dtb, Bn, Cn, delta);
    k_scan   <<<KK * DI, 512, 0, stream>>>(delta, Bn, Cn, xconv, xs1, alog, Dsp, y4);
    k_lnout  <<<dim3(LL / 16, 2), 256, 0, stream>>>(y4, z_nat, lnw, lnb, ow, out);
}

// Round 10
// 163.561 us; speedup vs baseline: 1.0625x; 1.0455x over previous
//
#include <hip/hip_runtime.h>
#include <hip/hip_bf16.h>
#include <math.h>

// SS2D (VMamba) forward, MI355X. Constants from the reference.
#define DM 96
#define DI 192
#define NS 16            // state dim N
#define KK 4             // directions
#define RR 6             // dt rank
#define HH 56
#define WW 56
#define LL (HH*WW)       // 3136
#define RN (RR + 2*NS)   // 38 rows of x_dbl
#define NCH 64           // scan chunks per sequence
#define CLL (LL/NCH)     // 49 steps per chunk

__device__ __forceinline__ float silu_f(float x) { return x / (1.f + __expf(-x)); }
__device__ __forceinline__ float softplus_f(float x) {
    return (x > 20.f) ? x : log1pf(__expf(x));
}

// K1: tiled GEMM xz[o][l]; 32l x 32o tiles, grid (98, 12).
// o<DI -> xc_t[o][l]; o>=DI -> silu -> z_nat[l][o-DI]
__global__ __launch_bounds__(256) void k_inproj(
        const float* __restrict__ x, const float* __restrict__ w,
        float* __restrict__ xc_t, float* __restrict__ z_nat) {
    __shared__ float xt[32 * 100];
    __shared__ float wt[32 * 100];
    const int l0 = blockIdx.x * 32;
    const int o0 = blockIdx.y * 32;
    const int tid = threadIdx.x;
    for (int i = tid; i < 32 * 24; i += 256) {          // float4 staging
        int r = i / 24, q = i % 24;
        *(float4*)&xt[r * 100 + 4 * q] = *(const float4*)&x[(size_t)(l0 + r) * DM + 4 * q];
        *(float4*)&wt[r * 100 + 4 * q] = *(const float4*)&w[(size_t)(o0 + r) * DM + 4 * q];
    }
    __syncthreads();
    const int tx = tid & 15, ty = tid >> 4;        // tx: o, ty: l
    float acc[2][2] = {};
    for (int c = 0; c < 96; c += 4) {
        float4 av[2], bv[2];
#pragma unroll
        for (int i = 0; i < 2; ++i) av[i] = *(const float4*)&xt[(ty + 16 * i) * 100 + c];
#pragma unroll
        for (int j = 0; j < 2; ++j) bv[j] = *(const float4*)&wt[(tx + 16 * j) * 100 + c];
#pragma unroll
        for (int i = 0; i < 2; ++i)
#pragma unroll
            for (int j = 0; j < 2; ++j) {
                acc[i][j] = fmaf(av[i].x, bv[j].x, acc[i][j]);
                acc[i][j] = fmaf(av[i].y, bv[j].y, acc[i][j]);
                acc[i][j] = fmaf(av[i].z, bv[j].z, acc[i][j]);
                acc[i][j] = fmaf(av[i].w, bv[j].w, acc[i][j]);
            }
    }
    __syncthreads();
    float* ot = xt;                                // reuse as [o][l] 32x65
#pragma unroll
    for (int j = 0; j < 2; ++j)
#pragma unroll
        for (int i = 0; i < 2; ++i)
            ot[(tx + 16 * j) * 65 + (ty + 16 * i)] = acc[i][j];
    __syncthreads();
    if (o0 < DI) {
        for (int i = tid; i < 32 * 32; i += 256) {
            int ol = i >> 5, ll = i & 31;
            xc_t[(size_t)(o0 + ol) * LL + l0 + ll] = ot[ol * 65 + ll];
        }
    } else {
        for (int i = tid; i < 32 * 32; i += 256) {
            int ll = i >> 5, ol = i & 31;
            z_nat[(size_t)(l0 + ll) * DI + (o0 - DI) + ol] = silu_f(ot[ol * 65 + ll]);
        }
    }
}

// K2: depthwise 3x3 conv SAME + bias + silu + spatial transpose, band-split.
__global__ __launch_bounds__(256) void k_convT(
        const float* __restrict__ xc_t, const float* __restrict__ cw,
        const float* __restrict__ cb, float* __restrict__ xconv, float* __restrict__ xs1) {
    __shared__ float in_s[16 * 56];
    __shared__ float out_s[14 * 57];
    const int d = blockIdx.x;
    const int h0 = blockIdx.y * 14;
    const int tid = threadIdx.x;
    const float* in = xc_t + (size_t)d * LL;
    for (int i = tid; i < 16 * 14; i += 256) {          // float4 staging
        int row = i / 14, q = i % 14;
        int r = row - 1 + h0;
        float4 v = make_float4(0.f, 0.f, 0.f, 0.f);
        if (r >= 0 && r < HH) v = *(const float4*)&in[r * WW + 4 * q];
        *(float4*)&in_s[row * 56 + 4 * q] = v;
    }
    __syncthreads();
    const float b0 = cb[d];
    float w9[9];
#pragma unroll
    for (int i = 0; i < 9; ++i) w9[i] = cw[d * 9 + i];
    for (int i = tid; i < 14 * 56; i += 256) {
        int hh = i / 56, w = i % 56;
        float acc = b0;
#pragma unroll
        for (int di = 0; di < 3; ++di)
#pragma unroll
            for (int dj = 0; dj < 3; ++dj) {
                int w2 = w + dj - 1;
                if (w2 < 0 || w2 >= WW) continue;
                acc = fmaf(in_s[(hh + di) * 56 + w2], w9[di * 3 + dj], acc);
            }
        acc = silu_f(acc);
        xconv[(size_t)d * LL + (h0 + hh) * WW + w] = acc;
        out_s[hh * 57 + w] = acc;
    }
    __syncthreads();
    for (int i = tid; i < 14 * 56; i += 256) {
        int w = i / 14, hh = i % 14;
        xs1[(size_t)d * LL + w * HH + h0 + hh] = out_s[hh * 57 + w];
    }
}

// K3: x_dbl + delta fused, l-tile 16. Both operands LDS-staged. Grid (196, 4).
// Bn/Cn written in SCAN-ORDER layout: [k][tl][chunk][n], pre-reversed for k>=2.
// delta stays in NATURAL layout (k_scan LDS-stages it coalesced).
__global__ __launch_bounds__(256) void k_xdblD(
        const float* __restrict__ xconv, const float* __restrict__ xs1,
        const float* __restrict__ pw, const float* __restrict__ dtw,
        const float* __restrict__ dtb,
        float* __restrict__ Bn, float* __restrict__ Cn, float* __restrict__ delta) {
    __shared__ float xt[DI * 16];                  // [d][sx], 12 KB
    __shared__ float wk_s[32 * DI];                // [col][d], 24.6 KB
    __shared__ float dtS[RR * 17];
    const int k = blockIdx.y;
    const int l0 = blockIdx.x * 16;
    const int tid = threadIdx.x;
    const float* in = (k & 1) ? xs1 : xconv;
    const float* wk = pw + (size_t)k * RN * DI;
    for (int i = tid; i < DI * 4; i += 256) {          // float4 staging
        int d = i >> 2, q = i & 3;
        *(float4*)&xt[(d << 4) + 4 * q] = *(const float4*)&in[(size_t)d * LL + l0 + 4 * q];
    }
    {
        const float4* src = (const float4*)(wk + RR * DI);
        float4* dst = (float4*)wk_s;
        for (int i = tid; i < (32 * DI) / 4; i += 256) dst[i] = src[i];
    }
    __syncthreads();
    if (tid < RR * 16) {
        int r = tid >> 4, lx = tid & 15;
        const float* wr = wk + r * DI;
        float acc = 0.f;
#pragma unroll 8
        for (int d = 0; d < DI; ++d) acc = fmaf(xt[(d << 4) + lx], wr[d], acc);
        dtS[r * 17 + lx] = acc;
    }
    {
        const int sx = tid & 15, cg = tid >> 4;    // cg in [0,16)
        float acc2[2] = {};
        for (int d = 0; d < DI; d += 4) {
            float x0 = xt[(d + 0) * 16 + sx];
            float x1 = xt[(d + 1) * 16 + sx];
            float x2 = xt[(d + 2) * 16 + sx];
            float x3 = xt[(d + 3) * 16 + sx];
#pragma unroll
            for (int j = 0; j < 2; ++j) {
                float4 wv = *(const float4*)&wk_s[(cg + 16 * j) * DI + d];
                acc2[j] = fmaf(x0, wv.x, acc2[j]);
                acc2[j] = fmaf(x1, wv.y, acc2[j]);
                acc2[j] = fmaf(x2, wv.z, acc2[j]);
                acc2[j] = fmaf(x3, wv.w, acc2[j]);
            }
        }
        int s = l0 + sx;
        int ss = (k < 2) ? s : (LL - 1 - s);       // scan-order index
        int cch = ss / CLL, ttl = ss - cch * CLL;
        size_t idx = ((size_t)k * LL + (size_t)ttl * NCH + cch) * NS + cg;
        Bn[idx] = acc2[0];                          // cols 0..15
        Cn[idx] = acc2[1];                          // cols 16..31
    }
    __syncthreads();
    for (int oi = tid; oi < DI * 16; oi += 256) {
        int d = oi >> 4, sl = oi & 15;
        int kd = k * DI + d;
        const float* wr = dtw + (size_t)kd * RR;
        float acc = dtb[kd];
#pragma unroll
        for (int r = 0; r < RR; ++r) acc = fmaf(dtS[r * 17 + sl], wr[r], acc);
        delta[(size_t)kd * LL + l0 + sl] = softplus_f(acc);
    }
}

// ---- templated scan body: 4 lanes per chunk, 4 contiguous states per lane.
// dl/u come from LDS (staged, broadcast across the 4 lanes of a chunk);
// B/C come from global in scan-order layout (step stride NCH*NS, coalesced).
// STP = +/-1 applies only to the LDS position indexing and y emission.
template<int STP, bool TRANS>
__device__ __forceinline__ void scan_dir(
        const float* sDel, const float* sU,        // LDS, pre-offset to im0
        const float* __restrict__ pB, const float* __restrict__ pC,
        float4 An, float Dv, int c, int n,
        float* __restrict__ sP, float* __restrict__ sH,
        float* __restrict__ yo0,   // !TRANS: direction-adjusted global base
        float* ysm,                // TRANS: LDS tile [HH][57] (aliases sDel buf)
        int im0) {
    // Phase 1: chunk-local scan (h=0 start); P = exp2(An * sum(dl))
    float sd = 0.f;
    float4 h = make_float4(0.f, 0.f, 0.f, 0.f);
#pragma unroll 7
    for (int tl = 0; tl < CLL; ++tl) {
        float dl = sDel[STP * tl];
        float u  = sU[STP * tl];
        float4 Bv = *(const float4*)&pB[(size_t)tl * (NCH * NS)];
        float du = dl * u;
        h.x = fmaf(__builtin_amdgcn_exp2f(dl * An.x), h.x, du * Bv.x);
        h.y = fmaf(__builtin_amdgcn_exp2f(dl * An.y), h.y, du * Bv.y);
        h.z = fmaf(__builtin_amdgcn_exp2f(dl * An.z), h.z, du * Bv.z);
        h.w = fmaf(__builtin_amdgcn_exp2f(dl * An.w), h.w, du * Bv.w);
        sd += dl;
    }
    *(float4*)&sP[c * NS + 4 * n] = make_float4(
        __builtin_amdgcn_exp2f(sd * An.x), __builtin_amdgcn_exp2f(sd * An.y),
        __builtin_amdgcn_exp2f(sd * An.z), __builtin_amdgcn_exp2f(sd * An.w));
    *(float4*)&sH[c * NS + 4 * n] = h;
    __syncthreads();
    float4 hin = make_float4(0.f, 0.f, 0.f, 0.f);
    for (int cc = 0; cc < c; ++cc) {
        float4 P  = *(const float4*)&sP[cc * NS + 4 * n];
        float4 Hh = *(const float4*)&sH[cc * NS + 4 * n];
        hin.x = fmaf(P.x, hin.x, Hh.x);
        hin.y = fmaf(P.y, hin.y, Hh.y);
        hin.z = fmaf(P.z, hin.z, Hh.z);
        hin.w = fmaf(P.w, hin.w, Hh.w);
    }

    // Phase 2: rescan with carry, emit y
    float4 h2 = hin;
    float yreg[13];
#pragma unroll 7
    for (int tl = 0; tl < CLL; ++tl) {
        float dl = sDel[STP * tl];
        float u  = sU[STP * tl];
        float4 Bv = *(const float4*)&pB[(size_t)tl * (NCH * NS)];
        float4 Cv = *(const float4*)&pC[(size_t)tl * (NCH * NS)];
        float du = dl * u;
        h2.x = fmaf(__builtin_amdgcn_exp2f(dl * An.x), h2.x, du * Bv.x);
        h2.y = fmaf(__builtin_amdgcn_exp2f(dl * An.y), h2.y, du * Bv.y);
        h2.z = fmaf(__builtin_amdgcn_exp2f(dl * An.z), h2.z, du * Bv.z);
        h2.w = fmaf(__builtin_amdgcn_exp2f(dl * An.w), h2.w, du * Bv.w);
        float acc = h2.x * Cv.x;
        acc = fmaf(h2.y, Cv.y, acc);
        acc = fmaf(h2.z, Cv.z, acc);
        acc = fmaf(h2.w, Cv.w, acc);
        acc += __shfl_xor(acc, 2, 64);
        acc += __shfl_xor(acc, 1, 64);
        acc = fmaf(Dv, u, acc);
        if ((tl & 3) == n) yreg[tl >> 2] = acc;
    }
    if (!TRANS) {
#pragma unroll
        for (int j = 0; j < 12; ++j)
            yo0[STP * (j * 4 + n)] = yreg[j];
        if (n == 0)
            yo0[STP * 48] = yreg[12];
    } else {
        __syncthreads();   // all waves done reading sDel/sU before ysm reuse
#pragma unroll
        for (int j = 0; j < 12; ++j) {
            int im = im0 + STP * (j * 4 + n);
            int w = im / HH, hh = im - w * HH;
            ysm[hh * 57 + w] = yreg[j];
        }
        if (n == 0) {
            int im = im0 + STP * 48;
            int w = im / HH, hh = im - w * HH;
            ysm[hh * 57 + w] = yreg[12];
        }
    }
}

// K4: chunked selective scan; 256 threads (4 waves), 64 chunks x 4 lanes.
// delta/u rows fully LDS-staged (coalesced); B/C read in scan-order layout.
// One (k,d) per block -> grid KK*DI = 768 (3 blocks/CU, 12 waves/CU).
__global__ __launch_bounds__(256) void k_scan(
        const float* __restrict__ delta, const float* __restrict__ Bn,
        const float* __restrict__ Cn,
        const float* __restrict__ xconv, const float* __restrict__ xs1,
        const float* __restrict__ A_logs, const float* __restrict__ Ds,
        float* __restrict__ y4) {
    __shared__ float sbuf[2 * LL];                 // del row | u row; reused as ys
    __shared__ float sP[NCH * NS];
    __shared__ float sH[NCH * NS];
    int b = blockIdx.x;
    int k = b / DI, d = b % DI;
    int tid = threadIdx.x;
    int c = tid >> 2, n = tid & 3;
    int kd = k * DI + d;
    const float LOG2E = 1.4426950408889634f;
    float4 Alg = *(const float4*)&A_logs[kd * NS + 4 * n];
    float4 An = make_float4(-__expf(Alg.x) * LOG2E, -__expf(Alg.y) * LOG2E,
                            -__expf(Alg.z) * LOG2E, -__expf(Alg.w) * LOG2E);
    float Dv = Ds[kd];
    const float* del = delta + (size_t)kd * LL;
    const float* uP  = ((k & 1) ? xs1 : xconv) + (size_t)d * LL;
    // coalesced staging of delta row and u row
    {
        const float4* s1 = (const float4*)del;
        const float4* s2 = (const float4*)uP;
        float4* d1 = (float4*)sbuf;
        float4* d2 = (float4*)(sbuf + LL);
        for (int i = tid; i < LL / 4; i += 256) {
            d1[i] = s1[i];
            d2[i] = s2[i];
        }
    }
    __syncthreads();
    const float* Bb = Bn + (size_t)k * LL * NS + c * NS + 4 * n;
    const float* Cb = Cn + (size_t)k * LL * NS + c * NS + 4 * n;
    float* yo = y4 + (size_t)kd * LL;
    const int t0 = c * CLL;
    const int imF = t0;                  // forward base
    const int imR = LL - 1 - t0;         // reverse base
    if (k == 0) {
        scan_dir<1, false>(sbuf + imF, sbuf + LL + imF, Bb, Cb,
                           An, Dv, c, n, sP, sH, yo + imF, nullptr, 0);
    } else if (k == 1) {
        scan_dir<1, true>(sbuf + imF, sbuf + LL + imF, Bb, Cb,
                          An, Dv, c, n, sP, sH, nullptr, sbuf, imF);
    } else if (k == 2) {
        scan_dir<-1, false>(sbuf + imR, sbuf + LL + imR, Bb, Cb,
                            An, Dv, c, n, sP, sH, yo + imR, nullptr, 0);
    } else {
        scan_dir<-1, true>(sbuf + imR, sbuf + LL + imR, Bb, Cb,
                           An, Dv, c, n, sP, sH, nullptr, sbuf, imR);
    }
    if (k & 1) {                         // block-uniform branch
        __syncthreads();
        for (int p = tid; p < LL; p += 256)
            yo[p] = sbuf[p + p / WW];    // [h][w] tile, stride 57
    }
}

// K5: merge 4 natural rows + LayerNorm + gate(z) ONCE, then out-proj in two
// sequential 48-o passes (ow_s restaged). 16 l per block; grid 196.
__global__ __launch_bounds__(256) void k_lnout(
        const float* __restrict__ y4, const float* __restrict__ z_nat,
        const float* __restrict__ lnw, const float* __restrict__ lnb,
        const float* __restrict__ ow, float* __restrict__ out) {
    __shared__ float yv[16 * 196];                 // 12.5 KB
    __shared__ float ow_s[48 * 196];               // 37.6 KB
    __shared__ float mean_s[16], inv_s[16];
    const int l0 = blockIdx.x * 16;
    const int tid = threadIdx.x;
    // merge 4 directions: float4 over p for each d
    for (int i = tid; i < DI * 4; i += 256) {
        int d = i >> 2, q = i & 3;
        size_t off = (size_t)d * LL + l0 + 4 * q;
        float4 a = *(const float4*)&y4[off];
        float4 b = *(const float4*)&y4[(size_t)DI * LL + off];
        float4 c2 = *(const float4*)&y4[(size_t)(2 * DI) * LL + off];
        float4 e = *(const float4*)&y4[(size_t)(3 * DI) * LL + off];
        int p = 4 * q;
        yv[(p + 0) * 196 + d] = a.x + b.x + c2.x + e.x;
        yv[(p + 1) * 196 + d] = a.y + b.y + c2.y + e.y;
        yv[(p + 2) * 196 + d] = a.z + b.z + c2.z + e.z;
        yv[(p + 3) * 196 + d] = a.w + b.w + c2.w + e.w;
    }
    __syncthreads();
    // LN stats: 16 lanes per p
    {
        int p = tid >> 4, e = tid & 15;
        float s1 = 0.f;
#pragma unroll
        for (int m = 0; m < 12; ++m) s1 += yv[p * 196 + e + 16 * m];
        s1 += __shfl_xor(s1, 8, 64);
        s1 += __shfl_xor(s1, 4, 64);
        s1 += __shfl_xor(s1, 2, 64);
        s1 += __shfl_xor(s1, 1, 64);
        float mean = s1 * (1.f / DI);
        float s2 = 0.f;
#pragma unroll
        for (int m = 0; m < 12; ++m) {
            float dv = yv[p * 196 + e + 16 * m] - mean;
            s2 = fmaf(dv, dv, s2);
        }
        s2 += __shfl_xor(s2, 8, 64);
        s2 += __shfl_xor(s2, 4, 64);
        s2 += __shfl_xor(s2, 2, 64);
        s2 += __shfl_xor(s2, 1, 64);
        if (e == 0) {
            mean_s[p] = mean;
            inv_s[p] = rsqrtf(s2 * (1.f / DI) + 1e-5f);
        }
    }
    __syncthreads();
    // normalize + gate (float4 over d) — done ONCE
    for (int i = tid; i < 16 * 48; i += 256) {
        int p = i / 48, q = i % 48;
        float4 z4 = *(const float4*)&z_nat[(size_t)(l0 + p) * DI + 4 * q];
        float4 w4 = *(const float4*)&lnw[4 * q];
        float4 b4 = *(const float4*)&lnb[4 * q];
        float4 yy = *(const float4*)&yv[p * 196 + 4 * q];
        float m = mean_s[p], iv = inv_s[p];
        yy.x = ((yy.x - m) * iv * w4.x + b4.x) * z4.x;
        yy.y = ((yy.y - m) * iv * w4.y + b4.y) * z4.y;
        yy.z = ((yy.z - m) * iv * w4.z + b4.z) * z4.z;
        yy.w = ((yy.w - m) * iv * w4.w + b4.w) * z4.w;
        *(float4*)&yv[p * 196 + 4 * q] = yy;
    }
    // out-proj: two sequential 48-o passes, restaging ow_s
    const int ty = tid >> 4, tx = tid & 15;        // ty: l, tx: o
#pragma unroll
    for (int pass = 0; pass < 2; ++pass) {
        __syncthreads();
        for (int i = tid; i < 48 * 48; i += 256) {
            int o = i / 48, q = i % 48;
            *(float4*)&ow_s[o * 196 + 4 * q] =
                *(const float4*)&ow[(size_t)(pass * 48 + o) * DI + 4 * q];
        }
        __syncthreads();
        float acc[3] = {};
        for (int dd = 0; dd < DI; dd += 4) {
            float4 a0 = *(const float4*)&yv[ty * 196 + dd];
#pragma unroll
            for (int j = 0; j < 3; ++j) {
                float4 bv = *(const float4*)&ow_s[(tx + 16 * j) * 196 + dd];
                acc[j] += a0.x * bv.x + a0.y * bv.y + a0.z * bv.z + a0.w * bv.w;
            }
        }
#pragma unroll
        for (int j = 0; j < 3; ++j)
            out[(size_t)(l0 + ty) * DM + pass * 48 + tx + 16 * j] = acc[j];
    }
}

extern "C" void kernel_launch(void* const* d_in, const int* in_sizes, int n_in,
                              void* d_out, int out_size, void* d_ws, size_t ws_size,
                              hipStream_t stream) {
    const float* x    = (const float*)d_in[0];
    const float* ipw  = (const float*)d_in[1];
    const float* cw   = (const float*)d_in[2];
    const float* cb   = (const float*)d_in[3];
    const float* xpw  = (const float*)d_in[4];
    const float* dtw  = (const float*)d_in[5];
    const float* dtb  = (const float*)d_in[6];
    const float* alog = (const float*)d_in[7];
    const float* Dsp  = (const float*)d_in[8];
    const float* lnw  = (const float*)d_in[9];
    const float* lnb  = (const float*)d_in[10];
    const float* ow   = (const float*)d_in[11];
    float* out = (float*)d_out;

    float* ws     = (float*)d_ws;
    float* xc_t   = ws;                             // DI*LL (dead after convT)
    float* z_nat  = xc_t + DI * LL;                 // LL*DI
    float* xconv  = z_nat + DI * LL;                // DI*LL
    float* xs1    = xconv + DI * LL;                // DI*LL
    float* Bn     = xs1 + DI * LL;                  // KK*LL*NS (scan-order layout)
    float* Cn     = Bn + (size_t)KK * LL * NS;      // KK*LL*NS (scan-order layout)
    float* delta  = Cn + (size_t)KK * LL * NS;      // KK*DI*LL (natural layout)
    float* y4     = delta + (size_t)KK * DI * LL;   // KK*DI*LL (natural p)

    k_inproj <<<dim3(LL / 32, 12), 256, 0, stream>>>(x, ipw, xc_t, z_nat);
    k_convT  <<<dim3(DI, 4), 256, 0, stream>>>(xc_t, cw, cb, xconv, xs1);
    k_xdblD  <<<dim3(LL / 16, KK), 256, 0, stream>>>(xconv, xs1, xpw, dtw, dtb, Bn, Cn, delta);
    k_scan   <<<KK * DI, 256, 0, stream>>>(delta, Bn, Cn, xconv, xs1, alog, Dsp, y4);
    k_lnout  <<<LL / 16, 256, 0, stream>>>(y4, z_nat, lnw, lnb, ow, out);
}

// Round 11
// 156.999 us; speedup vs baseline: 1.1069x; 1.0418x over previous
//
#include <hip/hip_runtime.h>
#include <hip/hip_bf16.h>
#include <math.h>

// SS2D (VMamba) forward, MI355X. Constants from the reference.
#define DM 96
#define DI 192
#define NS 16            // state dim N
#define KK 4             // directions
#define RR 6             // dt rank
#define HH 56
#define WW 56
#define LL (HH*WW)       // 3136
#define RN (RR + 2*NS)   // 38 rows of x_dbl
#define NCH 64           // scan chunks per sequence
#define CLL (LL/NCH)     // 49 steps per chunk (7 windows of 7)

__device__ __forceinline__ float silu_f(float x) { return x / (1.f + __expf(-x)); }
__device__ __forceinline__ float softplus_f(float x) {
    return (x > 20.f) ? x : log1pf(__expf(x));
}

// K1: tiled GEMM xz[o][l]; 32l x 32o tiles, grid (98, 12).
// o<DI -> xc_t[o][l]; o>=DI -> silu -> z_nat[l][o-DI]
__global__ __launch_bounds__(256) void k_inproj(
        const float* __restrict__ x, const float* __restrict__ w,
        float* __restrict__ xc_t, float* __restrict__ z_nat) {
    __shared__ float xt[32 * 100];
    __shared__ float wt[32 * 100];
    const int l0 = blockIdx.x * 32;
    const int o0 = blockIdx.y * 32;
    const int tid = threadIdx.x;
    for (int i = tid; i < 32 * 24; i += 256) {          // float4 staging
        int r = i / 24, q = i % 24;
        *(float4*)&xt[r * 100 + 4 * q] = *(const float4*)&x[(size_t)(l0 + r) * DM + 4 * q];
        *(float4*)&wt[r * 100 + 4 * q] = *(const float4*)&w[(size_t)(o0 + r) * DM + 4 * q];
    }
    __syncthreads();
    const int tx = tid & 15, ty = tid >> 4;        // tx: o, ty: l
    float acc[2][2] = {};
    for (int c = 0; c < 96; c += 4) {
        float4 av[2], bv[2];
#pragma unroll
        for (int i = 0; i < 2; ++i) av[i] = *(const float4*)&xt[(ty + 16 * i) * 100 + c];
#pragma unroll
        for (int j = 0; j < 2; ++j) bv[j] = *(const float4*)&wt[(tx + 16 * j) * 100 + c];
#pragma unroll
        for (int i = 0; i < 2; ++i)
#pragma unroll
            for (int j = 0; j < 2; ++j) {
                acc[i][j] = fmaf(av[i].x, bv[j].x, acc[i][j]);
                acc[i][j] = fmaf(av[i].y, bv[j].y, acc[i][j]);
                acc[i][j] = fmaf(av[i].z, bv[j].z, acc[i][j]);
                acc[i][j] = fmaf(av[i].w, bv[j].w, acc[i][j]);
            }
    }
    __syncthreads();
    float* ot = xt;                                // reuse as [o][l] 32x65
#pragma unroll
    for (int j = 0; j < 2; ++j)
#pragma unroll
        for (int i = 0; i < 2; ++i)
            ot[(tx + 16 * j) * 65 + (ty + 16 * i)] = acc[i][j];
    __syncthreads();
    if (o0 < DI) {
        for (int i = tid; i < 32 * 32; i += 256) {
            int ol = i >> 5, ll = i & 31;
            xc_t[(size_t)(o0 + ol) * LL + l0 + ll] = ot[ol * 65 + ll];
        }
    } else {
        for (int i = tid; i < 32 * 32; i += 256) {
            int ll = i >> 5, ol = i & 31;
            z_nat[(size_t)(l0 + ll) * DI + (o0 - DI) + ol] = silu_f(ot[ol * 65 + ll]);
        }
    }
}

// K2: depthwise 3x3 conv SAME + bias + silu + spatial transpose, band-split.
__global__ __launch_bounds__(256) void k_convT(
        const float* __restrict__ xc_t, const float* __restrict__ cw,
        const float* __restrict__ cb, float* __restrict__ xconv, float* __restrict__ xs1) {
    __shared__ float in_s[16 * 56];
    __shared__ float out_s[14 * 57];
    const int d = blockIdx.x;
    const int h0 = blockIdx.y * 14;
    const int tid = threadIdx.x;
    const float* in = xc_t + (size_t)d * LL;
    for (int i = tid; i < 16 * 14; i += 256) {          // float4 staging
        int row = i / 14, q = i % 14;
        int r = row - 1 + h0;
        float4 v = make_float4(0.f, 0.f, 0.f, 0.f);
        if (r >= 0 && r < HH) v = *(const float4*)&in[r * WW + 4 * q];
        *(float4*)&in_s[row * 56 + 4 * q] = v;
    }
    __syncthreads();
    const float b0 = cb[d];
    float w9[9];
#pragma unroll
    for (int i = 0; i < 9; ++i) w9[i] = cw[d * 9 + i];
    for (int i = tid; i < 14 * 56; i += 256) {
        int hh = i / 56, w = i % 56;
        float acc = b0;
#pragma unroll
        for (int di = 0; di < 3; ++di)
#pragma unroll
            for (int dj = 0; dj < 3; ++dj) {
                int w2 = w + dj - 1;
                if (w2 < 0 || w2 >= WW) continue;
                acc = fmaf(in_s[(hh + di) * 56 + w2], w9[di * 3 + dj], acc);
            }
        acc = silu_f(acc);
        xconv[(size_t)d * LL + (h0 + hh) * WW + w] = acc;
        out_s[hh * 57 + w] = acc;
    }
    __syncthreads();
    for (int i = tid; i < 14 * 56; i += 256) {
        int w = i / 14, hh = i % 14;
        xs1[(size_t)d * LL + w * HH + h0 + hh] = out_s[hh * 57 + w];
    }
}

// K3: x_dbl + delta fused, l-tile 16. Both operands LDS-staged. Grid (196, 4).
// Bn/Cn written in SCAN-ORDER layout: [k][tl][chunk][n], pre-reversed for k>=2.
// delta stays in NATURAL layout (k_scan LDS-stages it coalesced).
__global__ __launch_bounds__(256) void k_xdblD(
        const float* __restrict__ xconv, const float* __restrict__ xs1,
        const float* __restrict__ pw, const float* __restrict__ dtw,
        const float* __restrict__ dtb,
        float* __restrict__ Bn, float* __restrict__ Cn, float* __restrict__ delta) {
    __shared__ float xt[DI * 16];                  // [d][sx], 12 KB
    __shared__ float wk_s[32 * DI];                // [col][d], 24.6 KB
    __shared__ float dtS[RR * 17];
    const int k = blockIdx.y;
    const int l0 = blockIdx.x * 16;
    const int tid = threadIdx.x;
    const float* in = (k & 1) ? xs1 : xconv;
    const float* wk = pw + (size_t)k * RN * DI;
    for (int i = tid; i < DI * 4; i += 256) {          // float4 staging
        int d = i >> 2, q = i & 3;
        *(float4*)&xt[(d << 4) + 4 * q] = *(const float4*)&in[(size_t)d * LL + l0 + 4 * q];
    }
    {
        const float4* src = (const float4*)(wk + RR * DI);
        float4* dst = (float4*)wk_s;
        for (int i = tid; i < (32 * DI) / 4; i += 256) dst[i] = src[i];
    }
    __syncthreads();
    if (tid < RR * 16) {
        int r = tid >> 4, lx = tid & 15;
        const float* wr = wk + r * DI;
        float acc = 0.f;
#pragma unroll 8
        for (int d = 0; d < DI; ++d) acc = fmaf(xt[(d << 4) + lx], wr[d], acc);
        dtS[r * 17 + lx] = acc;
    }
    {
        const int sx = tid & 15, cg = tid >> 4;    // cg in [0,16)
        float acc2[2] = {};
        for (int d = 0; d < DI; d += 4) {
            float x0 = xt[(d + 0) * 16 + sx];
            float x1 = xt[(d + 1) * 16 + sx];
            float x2 = xt[(d + 2) * 16 + sx];
            float x3 = xt[(d + 3) * 16 + sx];
#pragma unroll
            for (int j = 0; j < 2; ++j) {
                float4 wv = *(const float4*)&wk_s[(cg + 16 * j) * DI + d];
                acc2[j] = fmaf(x0, wv.x, acc2[j]);
                acc2[j] = fmaf(x1, wv.y, acc2[j]);
                acc2[j] = fmaf(x2, wv.z, acc2[j]);
                acc2[j] = fmaf(x3, wv.w, acc2[j]);
            }
        }
        int s = l0 + sx;
        int ss = (k < 2) ? s : (LL - 1 - s);       // scan-order index
        int cch = ss / CLL, ttl = ss - cch * CLL;
        size_t idx = ((size_t)k * LL + (size_t)ttl * NCH + cch) * NS + cg;
        Bn[idx] = acc2[0];                          // cols 0..15
        Cn[idx] = acc2[1];                          // cols 16..31
    }
    __syncthreads();
    for (int oi = tid; oi < DI * 16; oi += 256) {
        int d = oi >> 4, sl = oi & 15;
        int kd = k * DI + d;
        const float* wr = dtw + (size_t)kd * RR;
        float acc = dtb[kd];
#pragma unroll
        for (int r = 0; r < RR; ++r) acc = fmaf(dtS[r * 17 + sl], wr[r], acc);
        delta[(size_t)kd * LL + l0 + sl] = softplus_f(acc);
    }
}

// ---- templated scan body: 4 lanes per chunk, 4 contiguous states per lane.
// dl/u come from LDS (staged, broadcast); B/C from global in scan-order
// layout (step stride NCH*NS, coalesced 4KB/wave).
// 7-DEEP REGISTER PREFETCH: each 49-step phase runs as 7 windows of 7;
// all window loads are batch-issued into statically-indexed register
// arrays before the compute, forcing 7-14 outstanding loads per wave
// (vs ~1 with the naive loop -> latency-bound at 22 B/cyc/CU).
template<int STP, bool TRANS>
__device__ __forceinline__ void scan_dir(
        const float* sDel, const float* sU,        // LDS, pre-offset to im0
        const float* __restrict__ pB, const float* __restrict__ pC,
        float4 An, float Dv, int c, int n,
        float* __restrict__ sP, float* __restrict__ sH,
        float* __restrict__ yo0,   // !TRANS: direction-adjusted global base
        float* ysm,                // TRANS: LDS tile [HH][57] (aliases sDel buf)
        int im0) {
    // Phase 1: chunk-local scan (h=0 start); P = exp2(An * sum(dl))
    float sd = 0.f;
    float4 h = make_float4(0.f, 0.f, 0.f, 0.f);
#pragma unroll
    for (int w = 0; w < 7; ++w) {
        float4 qb[7];
#pragma unroll
        for (int j = 0; j < 7; ++j)
            qb[j] = *(const float4*)&pB[(size_t)(w * 7 + j) * (NCH * NS)];
#pragma unroll
        for (int j = 0; j < 7; ++j) {
            const int tl = w * 7 + j;
            float dl = sDel[STP * tl];
            float u  = sU[STP * tl];
            float du = dl * u;
            h.x = fmaf(__builtin_amdgcn_exp2f(dl * An.x), h.x, du * qb[j].x);
            h.y = fmaf(__builtin_amdgcn_exp2f(dl * An.y), h.y, du * qb[j].y);
            h.z = fmaf(__builtin_amdgcn_exp2f(dl * An.z), h.z, du * qb[j].z);
            h.w = fmaf(__builtin_amdgcn_exp2f(dl * An.w), h.w, du * qb[j].w);
            sd += dl;
        }
    }
    *(float4*)&sP[c * NS + 4 * n] = make_float4(
        __builtin_amdgcn_exp2f(sd * An.x), __builtin_amdgcn_exp2f(sd * An.y),
        __builtin_amdgcn_exp2f(sd * An.z), __builtin_amdgcn_exp2f(sd * An.w));
    *(float4*)&sH[c * NS + 4 * n] = h;
    __syncthreads();
    float4 hin = make_float4(0.f, 0.f, 0.f, 0.f);
    for (int cc = 0; cc < c; ++cc) {
        float4 P  = *(const float4*)&sP[cc * NS + 4 * n];
        float4 Hh = *(const float4*)&sH[cc * NS + 4 * n];
        hin.x = fmaf(P.x, hin.x, Hh.x);
        hin.y = fmaf(P.y, hin.y, Hh.y);
        hin.z = fmaf(P.z, hin.z, Hh.z);
        hin.w = fmaf(P.w, hin.w, Hh.w);
    }

    // Phase 2: rescan with carry, emit y (B and C batch-prefetched)
    float4 h2 = hin;
    float yreg[13];
#pragma unroll
    for (int w = 0; w < 7; ++w) {
        float4 qb[7], qc[7];
#pragma unroll
        for (int j = 0; j < 7; ++j) {
            qb[j] = *(const float4*)&pB[(size_t)(w * 7 + j) * (NCH * NS)];
            qc[j] = *(const float4*)&pC[(size_t)(w * 7 + j) * (NCH * NS)];
        }
#pragma unroll
        for (int j = 0; j < 7; ++j) {
            const int tl = w * 7 + j;
            float dl = sDel[STP * tl];
            float u  = sU[STP * tl];
            float du = dl * u;
            h2.x = fmaf(__builtin_amdgcn_exp2f(dl * An.x), h2.x, du * qb[j].x);
            h2.y = fmaf(__builtin_amdgcn_exp2f(dl * An.y), h2.y, du * qb[j].y);
            h2.z = fmaf(__builtin_amdgcn_exp2f(dl * An.z), h2.z, du * qb[j].z);
            h2.w = fmaf(__builtin_amdgcn_exp2f(dl * An.w), h2.w, du * qb[j].w);
            float acc = h2.x * qc[j].x;
            acc = fmaf(h2.y, qc[j].y, acc);
            acc = fmaf(h2.z, qc[j].z, acc);
            acc = fmaf(h2.w, qc[j].w, acc);
            acc += __shfl_xor(acc, 2, 64);
            acc += __shfl_xor(acc, 1, 64);
            acc = fmaf(Dv, u, acc);
            if ((tl & 3) == n) yreg[tl >> 2] = acc;
        }
    }
    if (!TRANS) {
#pragma unroll
        for (int j = 0; j < 12; ++j)
            yo0[STP * (j * 4 + n)] = yreg[j];
        if (n == 0)
            yo0[STP * 48] = yreg[12];
    } else {
        __syncthreads();   // all waves done reading sDel/sU before ysm reuse
#pragma unroll
        for (int j = 0; j < 12; ++j) {
            int im = im0 + STP * (j * 4 + n);
            int w = im / HH, hh = im - w * HH;
            ysm[hh * 57 + w] = yreg[j];
        }
        if (n == 0) {
            int im = im0 + STP * 48;
            int w = im / HH, hh = im - w * HH;
            ysm[hh * 57 + w] = yreg[12];
        }
    }
}

// K4: chunked selective scan; 256 threads (4 waves), 64 chunks x 4 lanes.
// delta/u rows fully LDS-staged (coalesced); B/C read in scan-order layout
// with 7-deep register prefetch. Grid KK*DI = 768 (3 blocks/CU, 12 waves/CU).
// launch_bounds(256,3): cap VGPR ~170 so the prefetch arrays never spill.
__global__ __launch_bounds__(256, 3) void k_scan(
        const float* __restrict__ delta, const float* __restrict__ Bn,
        const float* __restrict__ Cn,
        const float* __restrict__ xconv, const float* __restrict__ xs1,
        const float* __restrict__ A_logs, const float* __restrict__ Ds,
        float* __restrict__ y4) {
    __shared__ float sbuf[2 * LL];                 // del row | u row; reused as ys
    __shared__ float sP[NCH * NS];
    __shared__ float sH[NCH * NS];
    int b = blockIdx.x;
    int k = b / DI, d = b % DI;
    int tid = threadIdx.x;
    int c = tid >> 2, n = tid & 3;
    int kd = k * DI + d;
    const float LOG2E = 1.4426950408889634f;
    float4 Alg = *(const float4*)&A_logs[kd * NS + 4 * n];
    float4 An = make_float4(-__expf(Alg.x) * LOG2E, -__expf(Alg.y) * LOG2E,
                            -__expf(Alg.z) * LOG2E, -__expf(Alg.w) * LOG2E);
    float Dv = Ds[kd];
    const float* del = delta + (size_t)kd * LL;
    const float* uP  = ((k & 1) ? xs1 : xconv) + (size_t)d * LL;
    // coalesced staging of delta row and u row
    {
        const float4* s1 = (const float4*)del;
        const float4* s2 = (const float4*)uP;
        float4* d1 = (float4*)sbuf;
        float4* d2 = (float4*)(sbuf + LL);
        for (int i = tid; i < LL / 4; i += 256) {
            d1[i] = s1[i];
            d2[i] = s2[i];
        }
    }
    __syncthreads();
    const float* Bb = Bn + (size_t)k * LL * NS + c * NS + 4 * n;
    const float* Cb = Cn + (size_t)k * LL * NS + c * NS + 4 * n;
    float* yo = y4 + (size_t)kd * LL;
    const int t0 = c * CLL;
    const int imF = t0;                  // forward base
    const int imR = LL - 1 - t0;         // reverse base
    if (k == 0) {
        scan_dir<1, false>(sbuf + imF, sbuf + LL + imF, Bb, Cb,
                           An, Dv, c, n, sP, sH, yo + imF, nullptr, 0);
    } else if (k == 1) {
        scan_dir<1, true>(sbuf + imF, sbuf + LL + imF, Bb, Cb,
                          An, Dv, c, n, sP, sH, nullptr, sbuf, imF);
    } else if (k == 2) {
        scan_dir<-1, false>(sbuf + imR, sbuf + LL + imR, Bb, Cb,
                            An, Dv, c, n, sP, sH, yo + imR, nullptr, 0);
    } else {
        scan_dir<-1, true>(sbuf + imR, sbuf + LL + imR, Bb, Cb,
                           An, Dv, c, n, sP, sH, nullptr, sbuf, imR);
    }
    if (k & 1) {                         // block-uniform branch
        __syncthreads();
        for (int p = tid; p < LL; p += 256)
            yo[p] = sbuf[p + p / WW];    // [h][w] tile, stride 57
    }
}

// K5: merge 4 natural rows + LayerNorm + gate(z) ONCE, then out-proj in two
// sequential 48-o passes (ow_s restaged). 16 l per block; grid 196.
__global__ __launch_bounds__(256) void k_lnout(
        const float* __restrict__ y4, const float* __restrict__ z_nat,
        const float* __restrict__ lnw, const float* __restrict__ lnb,
        const float* __restrict__ ow, float* __restrict__ out) {
    __shared__ float yv[16 * 196];                 // 12.5 KB
    __shared__ float ow_s[48 * 196];               // 37.6 KB
    __shared__ float mean_s[16], inv_s[16];
    const int l0 = blockIdx.x * 16;
    const int tid = threadIdx.x;
    // merge 4 directions: float4 over p for each d
    for (int i = tid; i < DI * 4; i += 256) {
        int d = i >> 2, q = i & 3;
        size_t off = (size_t)d * LL + l0 + 4 * q;
        float4 a = *(const float4*)&y4[off];
        float4 b = *(const float4*)&y4[(size_t)DI * LL + off];
        float4 c2 = *(const float4*)&y4[(size_t)(2 * DI) * LL + off];
        float4 e = *(const float4*)&y4[(size_t)(3 * DI) * LL + off];
        int p = 4 * q;
        yv[(p + 0) * 196 + d] = a.x + b.x + c2.x + e.x;
        yv[(p + 1) * 196 + d] = a.y + b.y + c2.y + e.y;
        yv[(p + 2) * 196 + d] = a.z + b.z + c2.z + e.z;
        yv[(p + 3) * 196 + d] = a.w + b.w + c2.w + e.w;
    }
    __syncthreads();
    // LN stats: 16 lanes per p
    {
        int p = tid >> 4, e = tid & 15;
        float s1 = 0.f;
#pragma unroll
        for (int m = 0; m < 12; ++m) s1 += yv[p * 196 + e + 16 * m];
        s1 += __shfl_xor(s1, 8, 64);
        s1 += __shfl_xor(s1, 4, 64);
        s1 += __shfl_xor(s1, 2, 64);
        s1 += __shfl_xor(s1, 1, 64);
        float mean = s1 * (1.f / DI);
        float s2 = 0.f;
#pragma unroll
        for (int m = 0; m < 12; ++m) {
            float dv = yv[p * 196 + e + 16 * m] - mean;
            s2 = fmaf(dv, dv, s2);
        }
        s2 += __shfl_xor(s2, 8, 64);
        s2 += __shfl_xor(s2, 4, 64);
        s2 += __shfl_xor(s2, 2, 64);
        s2 += __shfl_xor(s2, 1, 64);
        if (e == 0) {
            mean_s[p] = mean;
            inv_s[p] = rsqrtf(s2 * (1.f / DI) + 1e-5f);
        }
    }
    __syncthreads();
    // normalize + gate (float4 over d) — done ONCE
    for (int i = tid; i < 16 * 48; i += 256) {
        int p = i / 48, q = i % 48;
        float4 z4 = *(const float4*)&z_nat[(size_t)(l0 + p) * DI + 4 * q];
        float4 w4 = *(const float4*)&lnw[4 * q];
        float4 b4 = *(const float4*)&lnb[4 * q];
        float4 yy = *(const float4*)&yv[p * 196 + 4 * q];
        float m = mean_s[p], iv = inv_s[p];
        yy.x = ((yy.x - m) * iv * w4.x + b4.x) * z4.x;
        yy.y = ((yy.y - m) * iv * w4.y + b4.y) * z4.y;
        yy.z = ((yy.z - m) * iv * w4.z + b4.z) * z4.z;
        yy.w = ((yy.w - m) * iv * w4.w + b4.w) * z4.w;
        *(float4*)&yv[p * 196 + 4 * q] = yy;
    }
    // out-proj: two sequential 48-o passes, restaging ow_s
    const int ty = tid >> 4, tx = tid & 15;        // ty: l, tx: o
#pragma unroll
    for (int pass = 0; pass < 2; ++pass) {
        __syncthreads();
        for (int i = tid; i < 48 * 48; i += 256) {
            int o = i / 48, q = i % 48;
            *(float4*)&ow_s[o * 196 + 4 * q] =
                *(const float4*)&ow[(size_t)(pass * 48 + o) * DI + 4 * q];
        }
        __syncthreads();
        float acc[3] = {};
        for (int dd = 0; dd < DI; dd += 4) {
            float4 a0 = *(const float4*)&yv[ty * 196 + dd];
#pragma unroll
            for (int j = 0; j < 3; ++j) {
                float4 bv = *(const float4*)&ow_s[(tx + 16 * j) * 196 + dd];
                acc[j] += a0.x * bv.x + a0.y * bv.y + a0.z * bv.z + a0.w * bv.w;
            }
        }
#pragma unroll
        for (int j = 0; j < 3; ++j)
            out[(size_t)(l0 + ty) * DM + pass * 48 + tx + 16 * j] = acc[j];
    }
}

extern "C" void kernel_launch(void* const* d_in, const int* in_sizes, int n_in,
                              void* d_out, int out_size, void* d_ws, size_t ws_size,
                              hipStream_t stream) {
    const float* x    = (const float*)d_in[0];
    const float* ipw  = (const float*)d_in[1];
    const float* cw   = (const float*)d_in[2];
    const float* cb   = (const float*)d_in[3];
    const float* xpw  = (const float*)d_in[4];
    const float* dtw  = (const float*)d_in[5];
    const float* dtb  = (const float*)d_in[6];
    const float* alog = (const float*)d_in[7];
    const float* Dsp  = (const float*)d_in[8];
    const float* lnw  = (const float*)d_in[9];
    const float* lnb  = (const float*)d_in[10];
    const float* ow   = (const float*)d_in[11];
    float* out = (float*)d_out;

    float* ws     = (float*)d_ws;
    float* xc_t   = ws;                             // DI*LL (dead after convT)
    float* z_nat  = xc_t + DI * LL;                 // LL*DI
    float* xconv  = z_nat + DI * LL;                // DI*LL
    float* xs1    = xconv + DI * LL;                // DI*LL
    float* Bn     = xs1 + DI * LL;                  // KK*LL*NS (scan-order layout)
    float* Cn     = Bn + (size_t)KK * LL * NS;      // KK*LL*NS (scan-order layout)
    float* delta  = Cn + (size_t)KK * LL * NS;      // KK*DI*LL (natural layout)
    float* y4     = delta + (size_t)KK * DI * LL;   // KK*DI*LL (natural p)

    k_inproj <<<dim3(LL / 32, 12), 256, 0, stream>>>(x, ipw, xc_t, z_nat);
    k_convT  <<<dim3(DI, 4), 256, 0, stream>>>(xc_t, cw, cb, xconv, xs1);
    k_xdblD  <<<dim3(LL / 16, KK), 256, 0, stream>>>(xconv, xs1, xpw, dtw, dtb, Bn, Cn, delta);
    k_scan   <<<KK * DI, 256, 0, stream>>>(delta, Bn, Cn, xconv, xs1, alog, Dsp, y4);
    k_lnout  <<<LL / 16, 256, 0, stream>>>(y4, z_nat, lnw, lnb, ow, out);
}